// Round 2
// baseline (458.672 us; speedup 1.0000x reference)
//
#include <hip/hip_runtime.h>
#include <hip/hip_bf16.h>
#include <cstdint>
#include <cstddef>

using bf16 = __hip_bfloat16;
using short4v = __attribute__((ext_vector_type(4))) short;  // 4 bf16 (2 VGPRs)
using short8 = __attribute__((ext_vector_type(8))) short;   // 8 bf16 (4 VGPRs)
using floatx4 = __attribute__((ext_vector_type(4))) float;  // MFMA C/D frag

#define MFMA_BF16(A, B, C) __builtin_amdgcn_mfma_f32_16x16x32_bf16((A), (B), (C), 0, 0, 0)

__device__ inline short bf16_bits(float x) {
  bf16 v = __float2bfloat16(x);
  short r;
  __builtin_memcpy(&r, &v, 2);
  return r;
}

__device__ inline void store_c(bf16* p, float v) { *p = __float2bfloat16(v); }
__device__ inline void store_c(float* p, float v) { *p = v; }

// ---------------------------------------------------------------------------
// f32 -> bf16 bulk convert (RNE). 8 elements/thread, 16B stores.
// ---------------------------------------------------------------------------
__global__ __launch_bounds__(256) void f32_to_bf16_kernel(
    const float* __restrict__ src, bf16* __restrict__ dst, int n8) {
  const int i = blockIdx.x * 256 + threadIdx.x;
  if (i >= n8) return;
  const float4 a = ((const float4*)src)[2 * i];
  const float4 b = ((const float4*)src)[2 * i + 1];
  short8 r;
  r[0] = bf16_bits(a.x); r[1] = bf16_bits(a.y); r[2] = bf16_bits(a.z); r[3] = bf16_bits(a.w);
  r[4] = bf16_bits(b.x); r[5] = bf16_bits(b.y); r[6] = bf16_bits(b.z); r[7] = bf16_bits(b.w);
  *(short8*)(dst + (size_t)i * 8) = r;
}

// ---------------------------------------------------------------------------
// GEMM (m97 structure): C[m,n] = sum_k A[m,k]*B[n,k], A,B row-major bf16,
// row stride K; C row-major stride ldc. Tile 128x128, BK=64, 4 waves (2x2).
// global_load_lds width=16 staging with XOR chunk swizzle.
// ---------------------------------------------------------------------------
template <typename TC>
__global__ __launch_bounds__(256) void gemm_bt_async(
    const bf16* __restrict__ A, const bf16* __restrict__ B, TC* __restrict__ C,
    int ldc, int K) {
  __shared__ bf16 As[128 * 64];
  __shared__ bf16 Bs[128 * 64];
  const int tid = threadIdx.x;
  const int lane = tid & 63;
  const int wave = tid >> 6;
  const int lrow = lane & 15;
  const int quad = lane >> 4;
  const int wm = (wave >> 1) * 64;
  const int wn = (wave & 1) * 64;
  const int tm = blockIdx.y * 128;
  const int tn = blockIdx.x * 128;

  const int srow = tid >> 3;
  const int scl = tid & 7;

  floatx4 acc[4][4] = {};

  for (int k0 = 0; k0 < K; k0 += 64) {
    __syncthreads();
#pragma unroll
    for (int r = 0; r < 4; ++r) {
      const int row = r * 32 + srow;
      const int scg = scl ^ (row & 7);
      __builtin_amdgcn_global_load_lds(
          (const __attribute__((address_space(1))) void*)(A + (size_t)(tm + row) * K + k0 + scg * 8),
          (__attribute__((address_space(3))) void*)(As + row * 64 + scl * 8), 16, 0, 0);
    }
#pragma unroll
    for (int r = 0; r < 4; ++r) {
      const int row = r * 32 + srow;
      const int scg = scl ^ (row & 7);
      __builtin_amdgcn_global_load_lds(
          (const __attribute__((address_space(1))) void*)(B + (size_t)(tn + row) * K + k0 + scg * 8),
          (__attribute__((address_space(3))) void*)(Bs + row * 64 + scl * 8), 16, 0, 0);
    }
    __syncthreads();

#pragma unroll
    for (int kk = 0; kk < 2; ++kk) {
      short8 af[4], bfr[4];
#pragma unroll
      for (int i = 0; i < 4; ++i) {
        const int ra = wm + i * 16 + lrow;
        const int rb = wn + i * 16 + lrow;
        af[i] = *(const short8*)&As[ra * 64 + (((kk * 4 + quad) ^ (ra & 7)) * 8)];
        bfr[i] = *(const short8*)&Bs[rb * 64 + (((kk * 4 + quad) ^ (rb & 7)) * 8)];
      }
#pragma unroll
      for (int i = 0; i < 4; ++i)
#pragma unroll
        for (int j = 0; j < 4; ++j)
          acc[i][j] = MFMA_BF16(af[i], bfr[j], acc[i][j]);
    }
  }

#pragma unroll
  for (int i = 0; i < 4; ++i)
#pragma unroll
    for (int j = 0; j < 4; ++j)
#pragma unroll
      for (int r = 0; r < 4; ++r) {
        const int row = tm + wm + i * 16 + quad * 4 + r;
        const int col = tn + wn + j * 16 + lrow;
        store_c(&C[(size_t)row * ldc + col], acc[i][j][r]);
      }
}

// ---------------------------------------------------------------------------
// Mixed GEMM for the out-projection: A bf16 via global_load_lds; B f32 weight
// via register prefetch + convert + swizzled ds_write. C f32.
// ---------------------------------------------------------------------------
__global__ __launch_bounds__(256) void gemm_abf16_bf32(
    const bf16* __restrict__ A, const float* __restrict__ B, float* __restrict__ C,
    int ldc, int K) {
  __shared__ bf16 As[128 * 64];
  __shared__ bf16 Bs[128 * 64];
  const int tid = threadIdx.x;
  const int lane = tid & 63;
  const int wave = tid >> 6;
  const int lrow = lane & 15;
  const int quad = lane >> 4;
  const int wm = (wave >> 1) * 64;
  const int wn = (wave & 1) * 64;
  const int tm = blockIdx.y * 128;
  const int tn = blockIdx.x * 128;

  const int srow = tid >> 3;
  const int scl = tid & 7;
  const int c16 = tid & 15;
  const int br0 = tid >> 4;

  floatx4 acc[4][4] = {};
  float4 breg[8];
#pragma unroll
  for (int r = 0; r < 8; ++r)
    breg[r] = *(const float4*)(B + (size_t)(tn + r * 16 + br0) * K + c16 * 4);

  for (int k0 = 0; k0 < K; k0 += 64) {
    __syncthreads();
#pragma unroll
    for (int r = 0; r < 4; ++r) {
      const int row = r * 32 + srow;
      const int scg = scl ^ (row & 7);
      __builtin_amdgcn_global_load_lds(
          (const __attribute__((address_space(1))) void*)(A + (size_t)(tm + row) * K + k0 + scg * 8),
          (__attribute__((address_space(3))) void*)(As + row * 64 + scl * 8), 16, 0, 0);
    }
#pragma unroll
    for (int r = 0; r < 8; ++r) {
      const int row = r * 16 + br0;
      short4v sv;
      sv[0] = bf16_bits(breg[r].x); sv[1] = bf16_bits(breg[r].y);
      sv[2] = bf16_bits(breg[r].z); sv[3] = bf16_bits(breg[r].w);
      *(short4v*)&Bs[row * 64 + (((c16 >> 1) ^ (row & 7)) * 8) + (c16 & 1) * 4] = sv;
    }
    __syncthreads();
    if (k0 + 64 < K) {
#pragma unroll
      for (int r = 0; r < 8; ++r)
        breg[r] = *(const float4*)(B + (size_t)(tn + r * 16 + br0) * K + k0 + 64 + c16 * 4);
    }

#pragma unroll
    for (int kk = 0; kk < 2; ++kk) {
      short8 af[4], bfr[4];
#pragma unroll
      for (int i = 0; i < 4; ++i) {
        const int ra = wm + i * 16 + lrow;
        const int rb = wn + i * 16 + lrow;
        af[i] = *(const short8*)&As[ra * 64 + (((kk * 4 + quad) ^ (ra & 7)) * 8)];
        bfr[i] = *(const short8*)&Bs[rb * 64 + (((kk * 4 + quad) ^ (rb & 7)) * 8)];
      }
#pragma unroll
      for (int i = 0; i < 4; ++i)
#pragma unroll
        for (int j = 0; j < 4; ++j)
          acc[i][j] = MFMA_BF16(af[i], bfr[j], acc[i][j]);
    }
  }

#pragma unroll
  for (int i = 0; i < 4; ++i)
#pragma unroll
    for (int j = 0; j < 4; ++j)
#pragma unroll
      for (int r = 0; r < 4; ++r) {
        const int row = tm + wm + i * 16 + quad * 4 + r;
        const int col = tn + wn + j * 16 + lrow;
        C[(size_t)row * ldc + col] = acc[i][j][r];
      }
}

// ---------------------------------------------------------------------------
// RoPE, in-place on bf16 qkv. One thread per (b,s,h,q/k,pair).
// ---------------------------------------------------------------------------
__global__ void rope_kernel(bf16* __restrict__ qkv) {
  const int idx = blockIdx.x * 256 + threadIdx.x;
  const int i = idx & 15;
  int t = idx >> 4;
  const int qk = t & 1;
  t >>= 1;
  const int h = t & 15;
  t >>= 4;
  const int s = t & 2047;
  bf16* p = qkv + (size_t)t * 6144 + (h >> 1) * 768 + (h & 1) * 128 + qk * 256 + 2 * i;
  const float x0 = __bfloat162float(p[0]);
  const float x1 = __bfloat162float(p[1]);
  const float inv = powf(10000.f, -(float)(2 * i) / 32.f);
  const float ang = (float)s * inv;
  float sn, cs;
  sincosf(ang, &sn, &cs);
  p[0] = __float2bfloat16(x0 * cs - x1 * sn);
  p[1] = __float2bfloat16(x1 * cs + x0 * sn);
}

// ---------------------------------------------------------------------------
// Flash attention — DS-pipe-optimized revision.
// Round-1 lesson: doubling occupancy did NOT help -> DS (LDS) pipe is the
// shared bottleneck. This version minimizes DS traffic + conflicts:
//   * 128-row q-tile, 4 waves x 32 rows (halves per-work LDS frag reads vs
//     the 64-row variant), paired grid (8,H,B): qb = bx then 15-bx -> every
//     block exactly 34 k-iters.
//   * Vs layout [d 128][k 64] with 16B-chunk XOR swizzle
//     c' = (k>>3) ^ (d&7) ^ ((d>>3)&7): transpose-scatter writes go from
//     16-way bank conflict to 2-way (free); frag reads stay b128 and
//     conflict-free (d&7 distinct within each 8-lane phase).
//   * Ps layout [row 128][skgrp ^ (row&7)][8]: writes 8-way -> 4-way;
//     reads conflict-free. No barrier needed (same-wave RAW only).
//   * async K/V reg-prefetch (T14): next tile's global loads issued right
//     after staging; HBM latency hides under QK^T/softmax/PV.
//   * 2 barriers/iter, diag-only causal mask, setprio around MFMA clusters.
// ---------------------------------------------------------------------------
__global__ __launch_bounds__(256) void attn_flash_pair(
    const bf16* __restrict__ qkv, bf16* __restrict__ out) {
  __shared__ short Ks[16 * 64 * 8];  // [dgrp 16][key 64][8]       16 KB
  __shared__ short Vs[128 * 64];     // [d 128][swz 16B chunks]    16 KB
  __shared__ short Ps[128 * 64];     // [row 128][swz skgrp][8]    16 KB
  const int tid = threadIdx.x;
  const int wave = tid >> 6;
  const int lane = tid & 63;
  const int lrow = lane & 15;
  const int quad = lane >> 4;
  const int h = blockIdx.y;
  const int b = blockIdx.z;
  const size_t SROW = 6144;
  const bf16* base = qkv + (size_t)b * 2048 * SROW;
  const int qoff = (h >> 1) * 768 + (h & 1) * 128;
  const int koff = qoff + 256;
  const int voff = qoff + 512;
  const float scale = 0.088388347648318447f;  // 1/sqrt(128)

  const int sr = tid >> 2;  // staging row 0..63
  const int sq = tid & 3;   // staging quarter of the 128-wide d strip

  const bf16* kbase = base + (size_t)sr * SROW + koff + sq * 32;
  const bf16* vbase = base + (size_t)sr * SROW + voff + sq * 8;

  // Prefetch k-block 0 into registers (K/V addresses do not depend on qb).
  short8 kv[4], vv[4];
#pragma unroll
  for (int j = 0; j < 4; ++j) kv[j] = *(const short8*)(kbase + j * 8);
#pragma unroll
  for (int i = 0; i < 4; ++i) vv[i] = *(const short8*)(vbase + i * 32);

  for (int phase = 0; phase < 2; ++phase) {
    const int qb = phase ? (15 - (int)blockIdx.x) : (int)blockIdx.x;

    // Q A-frags: rows qb*128 + wave*32 + rt*16 + lrow, d = ks*32 + quad*8 + j
    short8 qf[2][4];
#pragma unroll
    for (int rt = 0; rt < 2; ++rt) {
      const bf16* qp =
          base + (size_t)(qb * 128 + wave * 32 + rt * 16 + lrow) * SROW + qoff + quad * 8;
#pragma unroll
      for (int ks = 0; ks < 4; ++ks) qf[rt][ks] = *(const short8*)(qp + ks * 32);
    }

    floatx4 o[2][8] = {};
    float m_i[8], l_i[8];
#pragma unroll
    for (int i = 0; i < 8; ++i) {
      m_i[i] = -1e30f;
      l_i[i] = 0.f;
    }

    const int kb_end = 2 * qb + 2;  // causal: only k-blocks overlapping tril
    for (int kb = 0; kb < kb_end; ++kb) {
      __syncthreads();  // all waves done reading Ks/Vs (prev iter or prev phase)

      // reg -> LDS stage of the prefetched tile.
      // K: proven m97-style layout/swizzle (b128 writes).
#pragma unroll
      for (int j = 0; j < 4; ++j) *(short8*)&Ks[((sq * 4 + j) * 64 + sr) * 8] = kv[j];
      // V: transpose scatter into [d][k] with both-side XOR chunk swizzle.
      {
        const int kc = sr >> 3;   // k 16B-chunk index (0..7)
        const int si = sr & 7;    // element within chunk
#pragma unroll
        for (int i = 0; i < 4; ++i) {
          const int dbase = sq * 8 + i * 32;              // dbase % 8 == 0
          const int cc = kc ^ ((dbase >> 3) & 7);         // (d>>3)&7 const over j<8
#pragma unroll
          for (int j = 0; j < 8; ++j) {
            // d = dbase + j; d&7 == j
            Vs[(dbase + j) * 64 + ((cc ^ j) * 8) + si] = vv[i][j];
          }
        }
      }
      __syncthreads();

      // Issue next tile's global loads now; they complete during compute and
      // are consumed by the reg->LDS stage after the next barrier.
      {
        const bool last = (kb + 1 == kb_end);
        const bool pf = !last || (phase == 0);
        const int nkb = !last ? kb + 1 : 0;  // phase-0 tail preloads kb=0 for phase 1
        if (pf) {
          const size_t off = (size_t)nkb * 64 * SROW;
#pragma unroll
          for (int j = 0; j < 4; ++j) kv[j] = *(const short8*)(kbase + off + j * 8);
#pragma unroll
          for (int i = 0; i < 4; ++i) vv[i] = *(const short8*)(vbase + off + i * 32);
        }
      }

      // S = Q K^T  (rows: wave's 32 q-rows; cols: 64 keys)
      floatx4 sc[2][4] = {};
      __builtin_amdgcn_s_setprio(1);
#pragma unroll
      for (int ks = 0; ks < 4; ++ks) {
        short8 bfr[4];
#pragma unroll
        for (int ct = 0; ct < 4; ++ct)
          bfr[ct] = *(const short8*)&Ks[((ks * 4 + quad) * 64 + ct * 16 + lrow) * 8];
#pragma unroll
        for (int rt = 0; rt < 2; ++rt)
#pragma unroll
          for (int ct = 0; ct < 4; ++ct)
            sc[rt][ct] = MFMA_BF16(qf[rt][ks], bfr[ct], sc[rt][ct]);
      }
      __builtin_amdgcn_s_setprio(0);

      // scale + causal mask (diagonal blocks only) + online softmax
      const int wr0 = qb * 128 + wave * 32;
      const bool diag = (kb * 64 + 63 > wr0);  // wave-uniform
#pragma unroll
      for (int rt = 0; rt < 2; ++rt)
#pragma unroll
        for (int r = 0; r < 4; ++r) {
          const int idx = rt * 4 + r;
          const int row_g = wr0 + rt * 16 + quad * 4 + r;
          float mx = -1e30f;
#pragma unroll
          for (int ct = 0; ct < 4; ++ct) {
            float v = sc[rt][ct][r] * scale;
            if (diag) {
              const int col_g = kb * 64 + ct * 16 + lrow;
              if (col_g > row_g) v = -1e9f;
            }
            sc[rt][ct][r] = v;
            mx = fmaxf(mx, v);
          }
#pragma unroll
          for (int off = 1; off < 16; off <<= 1) mx = fmaxf(mx, __shfl_xor(mx, off, 64));
          const float mnew = fmaxf(m_i[idx], mx);
          const float alpha = __expf(m_i[idx] - mnew);
          m_i[idx] = mnew;
          float rs = 0.f;
#pragma unroll
          for (int ct = 0; ct < 4; ++ct) {
            const float p = __expf(sc[rt][ct][r] - mnew);
            sc[rt][ct][r] = p;
            rs += p;
          }
#pragma unroll
          for (int off = 1; off < 16; off <<= 1) rs += __shfl_xor(rs, off, 64);
          l_i[idx] = l_i[idx] * alpha + rs;
#pragma unroll
          for (int dt = 0; dt < 8; ++dt) o[rt][dt][r] *= alpha;
        }

      // P (bf16) -> LDS, [row][swz skgrp][8] layout. No barrier: each wave
      // writes and reads only its own 32 q-rows (within-wave LDS RAW).
#pragma unroll
      for (int rt = 0; rt < 2; ++rt)
#pragma unroll
        for (int ct = 0; ct < 4; ++ct)
#pragma unroll
          for (int r = 0; r < 4; ++r) {
            const int row_l = wave * 32 + rt * 16 + quad * 4 + r;
            const int skgrp = ct * 2 + (lrow >> 3);
            const int cc = skgrp ^ (row_l & 7);
            Ps[row_l * 64 + cc * 8 + (lrow & 7)] = bf16_bits(sc[rt][ct][r]);
          }

      // O += P V
      __builtin_amdgcn_s_setprio(1);
#pragma unroll
      for (int ks = 0; ks < 2; ++ks) {
        short8 af[2], bfr[8];
#pragma unroll
        for (int rt = 0; rt < 2; ++rt) {
          const int row = wave * 32 + rt * 16 + lrow;
          const int cc = (ks * 4 + quad) ^ (row & 7);
          af[rt] = *(const short8*)&Ps[row * 64 + cc * 8];
        }
#pragma unroll
        for (int dt = 0; dt < 8; ++dt) {
          const int d = dt * 16 + lrow;
          const int cc = ((ks * 4 + quad) ^ (d & 7) ^ ((d >> 3) & 7)) & 7;
          bfr[dt] = *(const short8*)&Vs[d * 64 + cc * 8];
        }
#pragma unroll
        for (int rt = 0; rt < 2; ++rt)
#pragma unroll
          for (int dt = 0; dt < 8; ++dt)
            o[rt][dt] = MFMA_BF16(af[rt], bfr[dt], o[rt][dt]);
      }
      __builtin_amdgcn_s_setprio(0);
    }

    // epilogue: O / l, store to (b, s, h*128 + d) bf16
#pragma unroll
    for (int rt = 0; rt < 2; ++rt)
#pragma unroll
      for (int r = 0; r < 4; ++r) {
        const float inv_l = 1.f / l_i[rt * 4 + r];
        const int row = qb * 128 + wave * 32 + rt * 16 + quad * 4 + r;
#pragma unroll
        for (int dt = 0; dt < 8; ++dt) {
          const int d = dt * 16 + lrow;
          out[((size_t)(b * 2048 + row)) * 2048 + h * 128 + d] =
              __float2bfloat16(o[rt][dt][r] * inv_l);
        }
      }
  }
}

// ---------------------------------------------------------------------------
// Workspace budget: 64 MiB of d_ws (round-2-proven safe).
//   d_ws:  [0, 48 MiB)  qkv; [48, 64 MiB) flex: W_qkv half, then attnout
//   d_out: [0, 16 MiB)  hidden_bf16 scratch (dead before GEMM2 rewrites)
// ---------------------------------------------------------------------------
extern "C" void kernel_launch(void* const* d_in, const int* in_sizes, int n_in,
                              void* d_out, int out_size, void* d_ws, size_t ws_size,
                              hipStream_t stream) {
  const float* hidden = (const float*)d_in[0];  // (2,2048,2048) f32
  const float* Wqkv = (const float*)d_in[1];    // (6144,2048)  f32
  const float* Wout = (const float*)d_in[2];    // (2048,2048)  f32
  float* outp = (float*)d_out;                  // (2,2048,2048) f32

  bf16* qkv = (bf16*)d_ws;                    // 48 MiB
  bf16* flex = qkv + (size_t)4096 * 6144;     // 16 MiB flex
  bf16* hbf = (bf16*)d_out;                   // d_out scratch, 16 MiB

  f32_to_bf16_kernel<<<4096, 256, 0, stream>>>(hidden, hbf, 1048576);

  f32_to_bf16_kernel<<<3072, 256, 0, stream>>>(Wqkv, flex, 786432);
  gemm_bt_async<bf16><<<dim3(24, 32), 256, 0, stream>>>(hbf, flex, qkv, 6144, 2048);
  f32_to_bf16_kernel<<<3072, 256, 0, stream>>>(Wqkv + (size_t)3072 * 2048, flex, 786432);
  gemm_bt_async<bf16><<<dim3(24, 32), 256, 0, stream>>>(hbf, flex, qkv + 3072, 6144, 2048);

  rope_kernel<<<8192, 256, 0, stream>>>(qkv);

  bf16* attnout = flex;
  attn_flash_pair<<<dim3(8, 16, 2), 256, 0, stream>>>(qkv, attnout);

  gemm_abf16_bf32<<<dim3(16, 32), 256, 0, stream>>>(attnout, Wout, outp, 2048, 2048);
}

// Round 5
// 434.844 us; speedup vs baseline: 1.0548x; 1.0548x over previous
//
#include <hip/hip_runtime.h>
#include <hip/hip_bf16.h>
#include <cstdint>
#include <cstddef>

using bf16 = __hip_bfloat16;
using short4v = __attribute__((ext_vector_type(4))) short;  // 4 bf16 (2 VGPRs)
using short8 = __attribute__((ext_vector_type(8))) short;   // 8 bf16 (4 VGPRs)
using floatx4 = __attribute__((ext_vector_type(4))) float;  // MFMA C/D frag

#define MFMA_BF16(A, B, C) __builtin_amdgcn_mfma_f32_16x16x32_bf16((A), (B), (C), 0, 0, 0)

__device__ inline short bf16_bits(float x) {
  bf16 v = __float2bfloat16(x);
  short r;
  __builtin_memcpy(&r, &v, 2);
  return r;
}

__device__ inline void store_c(bf16* p, float v) { *p = __float2bfloat16(v); }
__device__ inline void store_c(float* p, float v) { *p = v; }

// ---------------------------------------------------------------------------
// f32 -> bf16 bulk convert (RNE). 8 elements/thread, 16B stores.
// ---------------------------------------------------------------------------
__global__ __launch_bounds__(256) void f32_to_bf16_kernel(
    const float* __restrict__ src, bf16* __restrict__ dst, int n8) {
  const int i = blockIdx.x * 256 + threadIdx.x;
  if (i >= n8) return;
  const float4 a = ((const float4*)src)[2 * i];
  const float4 b = ((const float4*)src)[2 * i + 1];
  short8 r;
  r[0] = bf16_bits(a.x); r[1] = bf16_bits(a.y); r[2] = bf16_bits(a.z); r[3] = bf16_bits(a.w);
  r[4] = bf16_bits(b.x); r[5] = bf16_bits(b.y); r[6] = bf16_bits(b.z); r[7] = bf16_bits(b.w);
  *(short8*)(dst + (size_t)i * 8) = r;
}

// ---------------------------------------------------------------------------
// GEMM (m97 structure): C[m,n] = sum_k A[m,k]*B[n,k], A,B row-major bf16,
// row stride K; C row-major stride ldc. Tile 128x128, BK=64, 4 waves (2x2).
// global_load_lds width=16 staging with XOR chunk swizzle.
// ---------------------------------------------------------------------------
template <typename TC>
__global__ __launch_bounds__(256) void gemm_bt_async(
    const bf16* __restrict__ A, const bf16* __restrict__ B, TC* __restrict__ C,
    int ldc, int K) {
  __shared__ bf16 As[128 * 64];
  __shared__ bf16 Bs[128 * 64];
  const int tid = threadIdx.x;
  const int lane = tid & 63;
  const int wave = tid >> 6;
  const int lrow = lane & 15;
  const int quad = lane >> 4;
  const int wm = (wave >> 1) * 64;
  const int wn = (wave & 1) * 64;
  const int tm = blockIdx.y * 128;
  const int tn = blockIdx.x * 128;

  const int srow = tid >> 3;
  const int scl = tid & 7;

  floatx4 acc[4][4] = {};

  for (int k0 = 0; k0 < K; k0 += 64) {
    __syncthreads();
#pragma unroll
    for (int r = 0; r < 4; ++r) {
      const int row = r * 32 + srow;
      const int scg = scl ^ (row & 7);
      __builtin_amdgcn_global_load_lds(
          (const __attribute__((address_space(1))) void*)(A + (size_t)(tm + row) * K + k0 + scg * 8),
          (__attribute__((address_space(3))) void*)(As + row * 64 + scl * 8), 16, 0, 0);
    }
#pragma unroll
    for (int r = 0; r < 4; ++r) {
      const int row = r * 32 + srow;
      const int scg = scl ^ (row & 7);
      __builtin_amdgcn_global_load_lds(
          (const __attribute__((address_space(1))) void*)(B + (size_t)(tn + row) * K + k0 + scg * 8),
          (__attribute__((address_space(3))) void*)(Bs + row * 64 + scl * 8), 16, 0, 0);
    }
    __syncthreads();

#pragma unroll
    for (int kk = 0; kk < 2; ++kk) {
      short8 af[4], bfr[4];
#pragma unroll
      for (int i = 0; i < 4; ++i) {
        const int ra = wm + i * 16 + lrow;
        const int rb = wn + i * 16 + lrow;
        af[i] = *(const short8*)&As[ra * 64 + (((kk * 4 + quad) ^ (ra & 7)) * 8)];
        bfr[i] = *(const short8*)&Bs[rb * 64 + (((kk * 4 + quad) ^ (rb & 7)) * 8)];
      }
#pragma unroll
      for (int i = 0; i < 4; ++i)
#pragma unroll
        for (int j = 0; j < 4; ++j)
          acc[i][j] = MFMA_BF16(af[i], bfr[j], acc[i][j]);
    }
  }

#pragma unroll
  for (int i = 0; i < 4; ++i)
#pragma unroll
    for (int j = 0; j < 4; ++j)
#pragma unroll
      for (int r = 0; r < 4; ++r) {
        const int row = tm + wm + i * 16 + quad * 4 + r;
        const int col = tn + wn + j * 16 + lrow;
        store_c(&C[(size_t)row * ldc + col], acc[i][j][r]);
      }
}

// ---------------------------------------------------------------------------
// Mixed GEMM for the out-projection: A bf16 via global_load_lds; B f32 weight
// via register prefetch + convert + swizzled ds_write. C f32.
// ---------------------------------------------------------------------------
__global__ __launch_bounds__(256) void gemm_abf16_bf32(
    const bf16* __restrict__ A, const float* __restrict__ B, float* __restrict__ C,
    int ldc, int K) {
  __shared__ bf16 As[128 * 64];
  __shared__ bf16 Bs[128 * 64];
  const int tid = threadIdx.x;
  const int lane = tid & 63;
  const int wave = tid >> 6;
  const int lrow = lane & 15;
  const int quad = lane >> 4;
  const int wm = (wave >> 1) * 64;
  const int wn = (wave & 1) * 64;
  const int tm = blockIdx.y * 128;
  const int tn = blockIdx.x * 128;

  const int srow = tid >> 3;
  const int scl = tid & 7;
  const int c16 = tid & 15;
  const int br0 = tid >> 4;

  floatx4 acc[4][4] = {};
  float4 breg[8];
#pragma unroll
  for (int r = 0; r < 8; ++r)
    breg[r] = *(const float4*)(B + (size_t)(tn + r * 16 + br0) * K + c16 * 4);

  for (int k0 = 0; k0 < K; k0 += 64) {
    __syncthreads();
#pragma unroll
    for (int r = 0; r < 4; ++r) {
      const int row = r * 32 + srow;
      const int scg = scl ^ (row & 7);
      __builtin_amdgcn_global_load_lds(
          (const __attribute__((address_space(1))) void*)(A + (size_t)(tm + row) * K + k0 + scg * 8),
          (__attribute__((address_space(3))) void*)(As + row * 64 + scl * 8), 16, 0, 0);
    }
#pragma unroll
    for (int r = 0; r < 8; ++r) {
      const int row = r * 16 + br0;
      short4v sv;
      sv[0] = bf16_bits(breg[r].x); sv[1] = bf16_bits(breg[r].y);
      sv[2] = bf16_bits(breg[r].z); sv[3] = bf16_bits(breg[r].w);
      *(short4v*)&Bs[row * 64 + (((c16 >> 1) ^ (row & 7)) * 8) + (c16 & 1) * 4] = sv;
    }
    __syncthreads();
    if (k0 + 64 < K) {
#pragma unroll
      for (int r = 0; r < 8; ++r)
        breg[r] = *(const float4*)(B + (size_t)(tn + r * 16 + br0) * K + k0 + 64 + c16 * 4);
    }

#pragma unroll
    for (int kk = 0; kk < 2; ++kk) {
      short8 af[4], bfr[4];
#pragma unroll
      for (int i = 0; i < 4; ++i) {
        const int ra = wm + i * 16 + lrow;
        const int rb = wn + i * 16 + lrow;
        af[i] = *(const short8*)&As[ra * 64 + (((kk * 4 + quad) ^ (ra & 7)) * 8)];
        bfr[i] = *(const short8*)&Bs[rb * 64 + (((kk * 4 + quad) ^ (rb & 7)) * 8)];
      }
#pragma unroll
      for (int i = 0; i < 4; ++i)
#pragma unroll
        for (int j = 0; j < 4; ++j)
          acc[i][j] = MFMA_BF16(af[i], bfr[j], acc[i][j]);
    }
  }

#pragma unroll
  for (int i = 0; i < 4; ++i)
#pragma unroll
    for (int j = 0; j < 4; ++j)
#pragma unroll
      for (int r = 0; r < 4; ++r) {
        const int row = tm + wm + i * 16 + quad * 4 + r;
        const int col = tn + wn + j * 16 + lrow;
        C[(size_t)row * ldc + col] = acc[i][j][r];
      }
}

// ---------------------------------------------------------------------------
// RoPE, in-place on bf16 qkv. One thread per (b,s,h,q/k,pair).
// ---------------------------------------------------------------------------
__global__ void rope_kernel(bf16* __restrict__ qkv) {
  const int idx = blockIdx.x * 256 + threadIdx.x;
  const int i = idx & 15;
  int t = idx >> 4;
  const int qk = t & 1;
  t >>= 1;
  const int h = t & 15;
  t >>= 4;
  const int s = t & 2047;
  bf16* p = qkv + (size_t)t * 6144 + (h >> 1) * 768 + (h & 1) * 128 + qk * 256 + 2 * i;
  const float x0 = __bfloat162float(p[0]);
  const float x1 = __bfloat162float(p[1]);
  const float inv = powf(10000.f, -(float)(2 * i) / 32.f);
  const float ang = (float)s * inv;
  float sn, cs;
  sincosf(ang, &sn, &cs);
  p[0] = __float2bfloat16(x0 * cs - x1 * sn);
  p[1] = __float2bfloat16(x1 * cs + x0 * sn);
}

// ---------------------------------------------------------------------------
// Flash attention — swapped-operand (transposed) revision.
// Rounds 1-2 showed the kernel is DS-instruction-issue-bound: occupancy x2
// (r1) and conflict x0.25 (r2) both left dur unchanged. This version halves
// the DS instruction stream:
//   * S^T = mfma(K_frag, Q_frag): A/B frags of 16x16x32 have identical
//     per-lane layout, so swapping operands transposes S for free. Lane
//     holds 16 key-values of ONE q-row -> softmax row-reduce becomes an
//     in-lane tree (VALU) + 2 shfl_xor (was 4x16 = 64 shuffles -> 8).
//   * P-store: lane owns 4 consecutive keys per ct -> 4 packed b64 writes
//     (was 32 scalar b16). Reads keep r0's conflict-free b128 pattern.
//   * O^T = mfma(V_frag, P_frag): output cols = q = lane&15 -> alpha
//     rescale is lane-uniform (no per-row indexing), m/l state 8 -> 2 regs.
//   * Q/K/V loads, staging (r0 linear V scatter), V-frag reads: bit-identical
//     to the proven r0 kernel. 2 barriers/iter, T14 reg-prefetch, diag-only
//     mask, setprio retained from r1/r2 (passing).
// Grid (8,16,2), paired phases qb = bx / 15-bx -> 34 k-iters per block.
// ---------------------------------------------------------------------------
__global__ __launch_bounds__(256) void attn_flash_pair(
    const bf16* __restrict__ qkv, bf16* __restrict__ out) {
  __shared__ short Ks[16 * 64 * 8];  // [dgrp 16][key 64][8]   16 KB
  __shared__ short Vs[8 * 128 * 8];  // [kgrp 8][d 128][8]     16 KB (V^T)
  __shared__ short Ps[8 * 128 * 8];  // [kgrp 8][qrow 128][8]  16 KB
  const int tid = threadIdx.x;
  const int wave = tid >> 6;
  const int lane = tid & 63;
  const int lq = lane & 15;   // q-col / A-row index within 16-tile
  const int quad = lane >> 4;
  const int h = blockIdx.y;
  const int b = blockIdx.z;
  const size_t SROW = 6144;
  const bf16* base = qkv + (size_t)b * 2048 * SROW;
  const int qoff = (h >> 1) * 768 + (h & 1) * 128;
  const int koff = qoff + 256;
  const int voff = qoff + 512;
  const float scale = 0.088388347648318447f;  // 1/sqrt(128)

  const int sr = tid >> 2;  // staging row 0..63
  const int sq = tid & 3;   // staging quarter of the 128-wide d strip

  const bf16* kbase = base + (size_t)sr * SROW + koff + sq * 32;
  const bf16* vbase = base + (size_t)sr * SROW + voff + sq * 8;

  // Prefetch k-block 0 into registers (K/V addresses do not depend on qb).
  short8 kv[4], vv[4];
#pragma unroll
  for (int j = 0; j < 4; ++j) kv[j] = *(const short8*)(kbase + j * 8);
#pragma unroll
  for (int i = 0; i < 4; ++i) vv[i] = *(const short8*)(vbase + i * 32);

  for (int phase = 0; phase < 2; ++phase) {
    const int qb = phase ? (15 - (int)blockIdx.x) : (int)blockIdx.x;

    // Q B-frags: q-col = lane&15, k = quad*8+j (identical load to r0's qf).
    short8 qf[2][4];
#pragma unroll
    for (int rt = 0; rt < 2; ++rt) {
      const bf16* qp =
          base + (size_t)(qb * 128 + wave * 32 + rt * 16 + lq) * SROW + qoff + quad * 8;
#pragma unroll
      for (int ks = 0; ks < 4; ++ks) qf[rt][ks] = *(const short8*)(qp + ks * 32);
    }

    floatx4 o[2][8] = {};
    float m_i[2] = {-1e30f, -1e30f};
    float l_i[2] = {0.f, 0.f};

    const int kb_end = 2 * qb + 2;  // causal: only k-blocks overlapping tril
    for (int kb = 0; kb < kb_end; ++kb) {
      __syncthreads();  // all waves done reading Ks/Vs (prev iter or prev phase)

      // reg -> LDS stage of the prefetched tile (r0 layouts).
#pragma unroll
      for (int j = 0; j < 4; ++j) *(short8*)&Ks[((sq * 4 + j) * 64 + sr) * 8] = kv[j];
      {
        const int so = (sr >> 3) * 128, si = sr & 7;
#pragma unroll
        for (int i = 0; i < 4; ++i) {
          const int d0 = sq * 8 + i * 32;
#pragma unroll
          for (int j = 0; j < 8; ++j) Vs[(so + d0 + j) * 8 + si] = vv[i][j];
        }
      }
      __syncthreads();

      // Issue next tile's global loads; consumed after the next barrier.
      {
        const bool last = (kb + 1 == kb_end);
        const bool pf = !last || (phase == 0);
        const int nkb = !last ? kb + 1 : 0;  // phase-0 tail preloads kb=0 for phase 1
        if (pf) {
          const size_t off = (size_t)nkb * 64 * SROW;
#pragma unroll
          for (int j = 0; j < 4; ++j) kv[j] = *(const short8*)(kbase + off + j * 8);
#pragma unroll
          for (int i = 0; i < 4; ++i) vv[i] = *(const short8*)(vbase + off + i * 32);
        }
      }

      // S^T = K Q : sc[rt][ct][r] = S[key = kb*64+ct*16+quad*4+r][q = ..+lq]
      floatx4 sc[2][4] = {};
      __builtin_amdgcn_s_setprio(1);
#pragma unroll
      for (int ks = 0; ks < 4; ++ks) {
        short8 kf[4];
#pragma unroll
        for (int ct = 0; ct < 4; ++ct)
          kf[ct] = *(const short8*)&Ks[((ks * 4 + quad) * 64 + ct * 16 + lq) * 8];
#pragma unroll
        for (int rt = 0; rt < 2; ++rt)
#pragma unroll
          for (int ct = 0; ct < 4; ++ct)
            sc[rt][ct] = MFMA_BF16(kf[ct], qf[rt][ks], sc[rt][ct]);
      }
      __builtin_amdgcn_s_setprio(0);

      // scale + causal mask (diagonal region only) + online softmax per q.
      const int qrow0 = qb * 128 + wave * 32;
      const bool diag = (kb * 64 + 63 > qrow0);  // wave-uniform
#pragma unroll
      for (int rt = 0; rt < 2; ++rt) {
        const int qg = qrow0 + rt * 16 + lq;
#pragma unroll
        for (int ct = 0; ct < 4; ++ct)
#pragma unroll
          for (int r = 0; r < 4; ++r) {
            float v = sc[rt][ct][r] * scale;
            if (diag && (kb * 64 + ct * 16 + quad * 4 + r) > qg) v = -1e9f;
            sc[rt][ct][r] = v;
          }
        // in-lane tree max over the 16 key-values
        float c0 = fmaxf(fmaxf(sc[rt][0][0], sc[rt][0][1]), fmaxf(sc[rt][0][2], sc[rt][0][3]));
        float c1 = fmaxf(fmaxf(sc[rt][1][0], sc[rt][1][1]), fmaxf(sc[rt][1][2], sc[rt][1][3]));
        float c2 = fmaxf(fmaxf(sc[rt][2][0], sc[rt][2][1]), fmaxf(sc[rt][2][2], sc[rt][2][3]));
        float c3 = fmaxf(fmaxf(sc[rt][3][0], sc[rt][3][1]), fmaxf(sc[rt][3][2], sc[rt][3][3]));
        float mx = fmaxf(fmaxf(c0, c1), fmaxf(c2, c3));
        // cross-quad (lanes lq, lq+16, lq+32, lq+48 hold disjoint keys)
        mx = fmaxf(mx, __shfl_xor(mx, 16, 64));
        mx = fmaxf(mx, __shfl_xor(mx, 32, 64));
        const float mnew = fmaxf(m_i[rt], mx);
        const float alpha = __expf(m_i[rt] - mnew);
        m_i[rt] = mnew;
        float s0 = 0.f, s1 = 0.f, s2 = 0.f, s3 = 0.f;
#pragma unroll
        for (int ct = 0; ct < 4; ++ct) {
          const float p0 = __expf(sc[rt][ct][0] - mnew);
          const float p1 = __expf(sc[rt][ct][1] - mnew);
          const float p2 = __expf(sc[rt][ct][2] - mnew);
          const float p3 = __expf(sc[rt][ct][3] - mnew);
          sc[rt][ct][0] = p0; sc[rt][ct][1] = p1; sc[rt][ct][2] = p2; sc[rt][ct][3] = p3;
          s0 += p0; s1 += p1; s2 += p2; s3 += p3;
        }
        float rs = (s0 + s1) + (s2 + s3);
        rs += __shfl_xor(rs, 16, 64);
        rs += __shfl_xor(rs, 32, 64);
        l_i[rt] = l_i[rt] * alpha + rs;
        // rescale O^T (cols = q = lane-uniform alpha)
#pragma unroll
        for (int dt = 0; dt < 8; ++dt) {
          o[rt][dt][0] *= alpha; o[rt][dt][1] *= alpha;
          o[rt][dt][2] *= alpha; o[rt][dt][3] *= alpha;
        }
        // P pack + b64 store: keys ct*16 + quad*4 + (0..3) of q-row `prow`.
        const int prow = wave * 32 + rt * 16 + lq;
#pragma unroll
        for (int ct = 0; ct < 4; ++ct) {
          short4v pv;
          pv[0] = bf16_bits(sc[rt][ct][0]); pv[1] = bf16_bits(sc[rt][ct][1]);
          pv[2] = bf16_bits(sc[rt][ct][2]); pv[3] = bf16_bits(sc[rt][ct][3]);
          const int kgrp = ct * 2 + (quad >> 1);
          *(short4v*)&Ps[(kgrp * 128 + prow) * 8 + (quad & 1) * 4] = pv;
        }
      }

      // O^T += V P : o[rt][dt] rows = d (quad*4+r), cols = q (lane&15).
      // Same-wave LDS RAW on Ps (each wave reads only its own 32 q-rows).
      __builtin_amdgcn_s_setprio(1);
#pragma unroll
      for (int kk = 0; kk < 2; ++kk) {
        short8 pf[2], vf[8];
#pragma unroll
        for (int rt = 0; rt < 2; ++rt)
          pf[rt] = *(const short8*)&Ps[((kk * 4 + quad) * 128 + wave * 32 + rt * 16 + lq) * 8];
#pragma unroll
        for (int dt = 0; dt < 8; ++dt)
          vf[dt] = *(const short8*)&Vs[((kk * 4 + quad) * 128 + dt * 16 + lq) * 8];
#pragma unroll
        for (int rt = 0; rt < 2; ++rt)
#pragma unroll
          for (int dt = 0; dt < 8; ++dt)
            o[rt][dt] = MFMA_BF16(vf[dt], pf[rt], o[rt][dt]);
      }
      __builtin_amdgcn_s_setprio(0);
    }

    // epilogue: out[q][d] = O^T[d][q] / l. Packed 4-wide bf16 stores.
#pragma unroll
    for (int rt = 0; rt < 2; ++rt) {
      const float inv_l = 1.f / l_i[rt];
      const int qg = qb * 128 + wave * 32 + rt * 16 + lq;
      bf16* op = out + ((size_t)(b * 2048 + qg)) * 2048 + h * 128 + quad * 4;
#pragma unroll
      for (int dt = 0; dt < 8; ++dt) {
        short4v s4;
        s4[0] = bf16_bits(o[rt][dt][0] * inv_l);
        s4[1] = bf16_bits(o[rt][dt][1] * inv_l);
        s4[2] = bf16_bits(o[rt][dt][2] * inv_l);
        s4[3] = bf16_bits(o[rt][dt][3] * inv_l);
        *(short4v*)(op + dt * 16) = s4;
      }
    }
  }
}

// ---------------------------------------------------------------------------
// Workspace budget: 64 MiB of d_ws (round-2-proven safe).
//   d_ws:  [0, 48 MiB)  qkv; [48, 64 MiB) flex: W_qkv half, then attnout
//   d_out: [0, 16 MiB)  hidden_bf16 scratch (dead before GEMM2 rewrites)
// ---------------------------------------------------------------------------
extern "C" void kernel_launch(void* const* d_in, const int* in_sizes, int n_in,
                              void* d_out, int out_size, void* d_ws, size_t ws_size,
                              hipStream_t stream) {
  const float* hidden = (const float*)d_in[0];  // (2,2048,2048) f32
  const float* Wqkv = (const float*)d_in[1];    // (6144,2048)  f32
  const float* Wout = (const float*)d_in[2];    // (2048,2048)  f32
  float* outp = (float*)d_out;                  // (2,2048,2048) f32

  bf16* qkv = (bf16*)d_ws;                    // 48 MiB
  bf16* flex = qkv + (size_t)4096 * 6144;     // 16 MiB flex
  bf16* hbf = (bf16*)d_out;                   // d_out scratch, 16 MiB

  f32_to_bf16_kernel<<<4096, 256, 0, stream>>>(hidden, hbf, 1048576);

  f32_to_bf16_kernel<<<3072, 256, 0, stream>>>(Wqkv, flex, 786432);
  gemm_bt_async<bf16><<<dim3(24, 32), 256, 0, stream>>>(hbf, flex, qkv, 6144, 2048);
  f32_to_bf16_kernel<<<3072, 256, 0, stream>>>(Wqkv + (size_t)3072 * 2048, flex, 786432);
  gemm_bt_async<bf16><<<dim3(24, 32), 256, 0, stream>>>(hbf, flex, qkv + 3072, 6144, 2048);

  rope_kernel<<<8192, 256, 0, stream>>>(qkv);

  bf16* attnout = flex;
  attn_flash_pair<<<dim3(8, 16, 2), 256, 0, stream>>>(qkv, attnout);

  gemm_abf16_bf32<<<dim3(16, 32), 256, 0, stream>>>(attnout, Wout, outp, 2048, 2048);
}